// Round 1
// baseline (3274.802 us; speedup 1.0000x reference)
//
#include <hip/hip_runtime.h>
#include <hip/hip_bf16.h>
#include <stdint.h>

typedef unsigned short u16;

#define T_TOK 8192
#define DIM 2048
#define INTER 1408
#define NEXP 32
#define TOPK 6
#define SHINTER 2816
#define SLOTS (T_TOK * TOPK)   // 49152

typedef __attribute__((ext_vector_type(8))) short bf16x8;
typedef __attribute__((ext_vector_type(4))) float f32x4;

__device__ inline u16 f2bf(float f) {
  union { float f; unsigned u; } c; c.f = f;
  unsigned r = (c.u + 0x7FFFu + ((c.u >> 16) & 1u)) >> 16;
  return (u16)r;
}
__device__ inline float bf2f(u16 h) {
  union { unsigned u; float f; } c; c.u = ((unsigned)h) << 16;
  return c.f;
}

// ---------------- gate + routing ----------------
__global__ __launch_bounds__(256)
void gate_route_k(const float* __restrict__ x, const float* __restrict__ gw,
                  int* __restrict__ tidx, float* __restrict__ tw, int* __restrict__ counts)
{
  int lane = threadIdx.x & 63, w = threadIdx.x >> 6;
  int t = blockIdx.x * 4 + w;
  __shared__ float sc[4][32];
  __shared__ float gm[4][8];
  const float* xr = x + (size_t)t * DIM + lane * 4;
  float4 xv[8];
#pragma unroll
  for (int i = 0; i < 8; i++) xv[i] = *(const float4*)(xr + i * 256);
  for (int e = 0; e < NEXP; e++) {
    const float* g = gw + (size_t)e * DIM + lane * 4;
    float acc = 0.f;
#pragma unroll
    for (int i = 0; i < 8; i++) {
      float4 gv = *(const float4*)(g + i * 256);
      acc += xv[i].x * gv.x + xv[i].y * gv.y + xv[i].z * gv.z + xv[i].w * gv.w;
    }
#pragma unroll
    for (int off = 32; off > 0; off >>= 1) acc += __shfl_down(acc, off);
    if (lane == 0) sc[w][e] = 1.f / (1.f + __expf(-acc));
  }
  if (lane == 0) {
#pragma unroll
    for (int g = 0; g < 8; g++)
      gm[w][g] = fmaxf(fmaxf(sc[w][g*4+0], sc[w][g*4+1]), fmaxf(sc[w][g*4+2], sc[w][g*4+3]));
    unsigned gsel = 0u;
    for (int it = 0; it < 4; it++) {
      float best = -1.f; int bi = 0;
      for (int g = 0; g < 8; g++)
        if (!((gsel >> g) & 1u) && gm[w][g] > best) { best = gm[w][g]; bi = g; }
      gsel |= 1u << bi;
    }
    unsigned chosen = 0u; float wsum = 0.f;
    int ids[TOPK]; float wv[TOPK];
#pragma unroll
    for (int it = 0; it < TOPK; it++) {
      float best = -1.f; int bi = 0;
      for (int e = 0; e < NEXP; e++)
        if (((gsel >> (e >> 2)) & 1u) && !((chosen >> e) & 1u) && sc[w][e] > best) { best = sc[w][e]; bi = e; }
      chosen |= 1u << bi; ids[it] = bi; wv[it] = best; wsum += best;
    }
    float s = 2.5f / wsum;
#pragma unroll
    for (int k = 0; k < TOPK; k++) {
      tidx[t * TOPK + k] = ids[k];
      tw[t * TOPK + k] = wv[k] * s;
      atomicAdd(&counts[ids[k]], 1);
    }
  }
}

__global__ void zero32(int* p) { if (threadIdx.x < NEXP) p[threadIdx.x] = 0; }

// ---------------- scan + tile descriptors ----------------
__global__ void scan_desc_k(const int* __restrict__ counts, int* __restrict__ offs,
                            int4* __restrict__ desc, int* __restrict__ ntiles)
{
  if (threadIdx.x != 0 || blockIdx.x != 0) return;
  int off = 0, n = 0;
  for (int e = 0; e < NEXP; e++) {
    offs[e] = off;
    int c = counts[e];
    int nt = (c + 127) >> 7;
    for (int i = 0; i < nt; i++) {
      int rem = c - i * 128;
      desc[n] = make_int4(e, off + i * 128, rem < 128 ? rem : 128, 0);
      n++;
    }
    off += c;
  }
  offs[NEXP] = off;
  ntiles[0] = n;
}

// ---------------- deterministic permutation build ----------------
__global__ __launch_bounds__(256)
void perm_build_k(const int* __restrict__ tidx, const float* __restrict__ tw,
                  const int* __restrict__ offs, int* __restrict__ ptok,
                  float* __restrict__ pw, int* __restrict__ slotof)
{
  int e = blockIdx.x;
  int tid = threadIdx.x, lane = tid & 63, w = tid >> 6;
  __shared__ int wsum[4];
  __shared__ int cursor;
  if (tid == 0) cursor = offs[e];
  __syncthreads();
  for (int start = 0; start < SLOTS; start += 256) {
    int i = start + tid;
    int match = (tidx[i] == e) ? 1 : 0;
    unsigned long long b = __ballot(match);
    if (lane == 0) wsum[w] = __popcll(b);
    __syncthreads();
    int base = cursor;
    int waveoff = 0;
    for (int ww = 0; ww < w; ww++) waveoff += wsum[ww];
    int total = wsum[0] + wsum[1] + wsum[2] + wsum[3];
    if (match) {
      int before = __popcll(b & ((1ull << lane) - 1ull));
      int slot = base + waveoff + before;
      ptok[slot] = i / TOPK;
      pw[slot] = tw[i];
      slotof[i] = slot;
    }
    __syncthreads();
    if (tid == 0) cursor = base + total;
  }
}

// ---------------- x -> bf16 ----------------
__global__ __launch_bounds__(256)
void cvt_x_k(const float* __restrict__ x, u16* __restrict__ xb)
{
  size_t i = ((size_t)blockIdx.x * 256 + threadIdx.x) * 8;
  float4 a = *(const float4*)(x + i);
  float4 b = *(const float4*)(x + i + 4);
  union { u16 h[8]; uint4 u; } p;
  p.h[0] = f2bf(a.x); p.h[1] = f2bf(a.y); p.h[2] = f2bf(a.z); p.h[3] = f2bf(a.w);
  p.h[4] = f2bf(b.x); p.h[5] = f2bf(b.y); p.h[6] = f2bf(b.z); p.h[7] = f2bf(b.w);
  *(uint4*)(xb + i) = p.u;
}

// ---------------- fused up-GEMM: H = silu(X W1^T) * (X W3^T) ----------------
template<bool SHARED>
__global__ __launch_bounds__(256, 2)
void up_gemm_k(const u16* __restrict__ xb,
               const float* __restrict__ W1g, const float* __restrict__ W3g,
               const int* __restrict__ ptok,
               const int4* __restrict__ desc, const int* __restrict__ ntiles,
               u16* __restrict__ Hout)
{
  constexpr int HLD = SHARED ? SHINTER : INTER;
  int row_tile = blockIdx.x, col_tile = blockIdx.y;
  int slot_base, rows;
  const float *B1, *B3;
  if constexpr (SHARED) {
    slot_base = row_tile * 128; rows = 128; B1 = W1g; B3 = W3g;
  } else {
    if (row_tile >= ntiles[0]) return;
    int4 d = desc[row_tile];
    slot_base = d.y; rows = d.z;
    size_t off = (size_t)d.x * (size_t)INTER * DIM;
    B1 = W1g + off; B3 = W3g + off;
  }
  int n0 = col_tile * 128;
  int tid = threadIdx.x, lane = tid & 63;
  int wv = tid >> 6, wr = wv >> 1, wc = wv & 1;

  __shared__ u16 As[128][72];
  __shared__ u16 Bs1[128][72];
  __shared__ u16 Bs3[128][72];

  int ar = tid >> 3, ac = (tid & 7) * 8;            // A stage: 4 sweeps of 32 rows
  const u16* asrc[4];
#pragma unroll
  for (int s = 0; s < 4; s++) {
    int r = s * 32 + ar;
    int tok;
    if constexpr (SHARED) tok = slot_base + r;
    else { int rr = r < rows ? r : rows - 1; tok = ptok[slot_base + rr]; }
    asrc[s] = xb + (size_t)tok * DIM + ac;
  }
  int br = tid >> 4, bc = (tid & 15) * 4;           // B stage: 8 sweeps of 16 rows
  const float* b1p = B1 + (size_t)(n0 + br) * DIM + bc;
  const float* b3p = B3 + (size_t)(n0 + br) * DIM + bc;

  f32x4 acc1[4][4], acc3[4][4];
#pragma unroll
  for (int m = 0; m < 4; m++)
#pragma unroll
    for (int n = 0; n < 4; n++) { acc1[m][n] = {0.f,0.f,0.f,0.f}; acc3[m][n] = {0.f,0.f,0.f,0.f}; }

  for (int kk = 0; kk < DIM / 64; kk++) {
    __syncthreads();
#pragma unroll
    for (int s = 0; s < 4; s++) {
      uint4 v = *(const uint4*)(asrc[s] + kk * 64);
      *(uint4*)&As[s * 32 + ar][ac] = v;
    }
#pragma unroll
    for (int s = 0; s < 8; s++) {
      float4 v = *(const float4*)(b1p + (size_t)(s * 16) * DIM + kk * 64);
      union { u16 h[4]; uint2 q; } o;
      o.h[0] = f2bf(v.x); o.h[1] = f2bf(v.y); o.h[2] = f2bf(v.z); o.h[3] = f2bf(v.w);
      *(uint2*)&Bs1[s * 16 + br][bc] = o.q;
    }
#pragma unroll
    for (int s = 0; s < 8; s++) {
      float4 v = *(const float4*)(b3p + (size_t)(s * 16) * DIM + kk * 64);
      union { u16 h[4]; uint2 q; } o;
      o.h[0] = f2bf(v.x); o.h[1] = f2bf(v.y); o.h[2] = f2bf(v.z); o.h[3] = f2bf(v.w);
      *(uint2*)&Bs3[s * 16 + br][bc] = o.q;
    }
    __syncthreads();
#pragma unroll
    for (int h = 0; h < 2; h++) {
      bf16x8 af[4], b1f[4], b3f[4];
#pragma unroll
      for (int m = 0; m < 4; m++)
        af[m] = *(const bf16x8*)&As[wr * 64 + m * 16 + (lane & 15)][h * 32 + (lane >> 4) * 8];
#pragma unroll
      for (int n = 0; n < 4; n++) {
        b1f[n] = *(const bf16x8*)&Bs1[wc * 64 + n * 16 + (lane & 15)][h * 32 + (lane >> 4) * 8];
        b3f[n] = *(const bf16x8*)&Bs3[wc * 64 + n * 16 + (lane & 15)][h * 32 + (lane >> 4) * 8];
      }
#pragma unroll
      for (int m = 0; m < 4; m++)
#pragma unroll
        for (int n = 0; n < 4; n++) {
          acc1[m][n] = __builtin_amdgcn_mfma_f32_16x16x32_bf16(af[m], b1f[n], acc1[m][n], 0, 0, 0);
          acc3[m][n] = __builtin_amdgcn_mfma_f32_16x16x32_bf16(af[m], b3f[n], acc3[m][n], 0, 0, 0);
        }
    }
  }
#pragma unroll
  for (int m = 0; m < 4; m++) {
#pragma unroll
    for (int r = 0; r < 4; r++) {
      int row_local = wr * 64 + m * 16 + (lane >> 4) * 4 + r;
      if (row_local < rows) {
        size_t rowp = (size_t)(slot_base + row_local) * HLD + n0 + wc * 64 + (lane & 15);
#pragma unroll
        for (int n = 0; n < 4; n++) {
          float c1 = acc1[m][n][r], c3 = acc3[m][n][r];
          float hval = (c1 / (1.f + __expf(-c1))) * c3;
          Hout[rowp + n * 16] = f2bf(hval);
        }
      }
    }
  }
}

// ---------------- down-GEMM: O = H W2^T ----------------
template<bool SHARED>
__global__ __launch_bounds__(256, 2)
void down_gemm_k(const u16* __restrict__ Hin, const float* __restrict__ Bg,
                 const int4* __restrict__ desc, const int* __restrict__ ntiles,
                 const float* __restrict__ pw,
                 u16* __restrict__ slotout, float* __restrict__ yout)
{
  constexpr int KD = SHARED ? SHINTER : INTER;
  constexpr int KSTEPS = KD / 64;
  int row_tile = blockIdx.x, col_tile = blockIdx.y;
  int slot_base, rows; const float* B;
  if constexpr (SHARED) { slot_base = row_tile * 128; rows = 128; B = Bg; }
  else {
    if (row_tile >= ntiles[0]) return;
    int4 d = desc[row_tile]; slot_base = d.y; rows = d.z;
    B = Bg + (size_t)d.x * DIM * INTER;
  }
  int n0 = col_tile * 128;
  int tid = threadIdx.x, lane = tid & 63;
  int wv = tid >> 6, wr = wv >> 1, wc = wv & 1;
  __shared__ u16 As[128][72];
  __shared__ u16 Bs[128][72];
  int ar = tid >> 3, ac = (tid & 7) * 8;
  const u16* asrc[4];
#pragma unroll
  for (int s = 0; s < 4; s++)
    asrc[s] = Hin + (size_t)(slot_base + s * 32 + ar) * KD + ac;
  int br = tid >> 4, bc = (tid & 15) * 4;
  const float* bp = B + (size_t)(n0 + br) * KD + bc;

  f32x4 acc[4][4];
#pragma unroll
  for (int m = 0; m < 4; m++)
#pragma unroll
    for (int n = 0; n < 4; n++) acc[m][n] = {0.f,0.f,0.f,0.f};

  for (int kk = 0; kk < KSTEPS; kk++) {
    __syncthreads();
#pragma unroll
    for (int s = 0; s < 4; s++) {
      uint4 v = *(const uint4*)(asrc[s] + kk * 64);
      *(uint4*)&As[s * 32 + ar][ac] = v;
    }
#pragma unroll
    for (int s = 0; s < 8; s++) {
      float4 v = *(const float4*)(bp + (size_t)(s * 16) * KD + kk * 64);
      union { u16 h[4]; uint2 q; } o;
      o.h[0] = f2bf(v.x); o.h[1] = f2bf(v.y); o.h[2] = f2bf(v.z); o.h[3] = f2bf(v.w);
      *(uint2*)&Bs[s * 16 + br][bc] = o.q;
    }
    __syncthreads();
#pragma unroll
    for (int h = 0; h < 2; h++) {
      bf16x8 af[4], bfv[4];
#pragma unroll
      for (int m = 0; m < 4; m++)
        af[m] = *(const bf16x8*)&As[wr * 64 + m * 16 + (lane & 15)][h * 32 + (lane >> 4) * 8];
#pragma unroll
      for (int n = 0; n < 4; n++)
        bfv[n] = *(const bf16x8*)&Bs[wc * 64 + n * 16 + (lane & 15)][h * 32 + (lane >> 4) * 8];
#pragma unroll
      for (int m = 0; m < 4; m++)
#pragma unroll
        for (int n = 0; n < 4; n++)
          acc[m][n] = __builtin_amdgcn_mfma_f32_16x16x32_bf16(af[m], bfv[n], acc[m][n], 0, 0, 0);
    }
  }
#pragma unroll
  for (int m = 0; m < 4; m++) {
#pragma unroll
    for (int r = 0; r < 4; r++) {
      int row_local = wr * 64 + m * 16 + (lane >> 4) * 4 + r;
      if (row_local < rows) {
        int slot = slot_base + row_local;
        size_t rp = (size_t)slot * DIM + n0 + wc * 64 + (lane & 15);
        if constexpr (SHARED) {
#pragma unroll
          for (int n = 0; n < 4; n++) yout[rp + n * 16] = acc[m][n][r];
        } else {
          float sw = pw[slot];
#pragma unroll
          for (int n = 0; n < 4; n++) slotout[rp + n * 16] = f2bf(acc[m][n][r] * sw);
        }
      }
    }
  }
}

// ---------------- final combine: y[t] = shared + sum_k slotout ----------------
__global__ __launch_bounds__(256)
void combine_k(float* __restrict__ y, const u16* __restrict__ slotout, const int* __restrict__ slotof)
{
  int t = blockIdx.x;
  int c = threadIdx.x * 8;
  size_t rp = (size_t)t * DIM + c;
  float4 a = *(const float4*)(y + rp);
  float4 b = *(const float4*)(y + rp + 4);
  float o[8] = {a.x, a.y, a.z, a.w, b.x, b.y, b.z, b.w};
#pragma unroll
  for (int k = 0; k < TOPK; k++) {
    int s = slotof[t * TOPK + k];
    uint4 v = *(const uint4*)(slotout + (size_t)s * DIM + c);
    o[0] += bf2f((u16)(v.x & 0xFFFFu)); o[1] += bf2f((u16)(v.x >> 16));
    o[2] += bf2f((u16)(v.y & 0xFFFFu)); o[3] += bf2f((u16)(v.y >> 16));
    o[4] += bf2f((u16)(v.z & 0xFFFFu)); o[5] += bf2f((u16)(v.z >> 16));
    o[6] += bf2f((u16)(v.w & 0xFFFFu)); o[7] += bf2f((u16)(v.w >> 16));
  }
  *(float4*)(y + rp)     = make_float4(o[0], o[1], o[2], o[3]);
  *(float4*)(y + rp + 4) = make_float4(o[4], o[5], o[6], o[7]);
}

// ---------------- host ----------------
extern "C" void kernel_launch(void* const* d_in, const int* in_sizes, int n_in,
                              void* d_out, int out_size, void* d_ws, size_t ws_size,
                              hipStream_t stream)
{
  const float* x   = (const float*)d_in[0];
  const float* gw  = (const float*)d_in[1];
  const float* w1  = (const float*)d_in[2];
  const float* w2  = (const float*)d_in[3];
  const float* w3  = (const float*)d_in[4];
  const float* sw1 = (const float*)d_in[5];
  const float* sw2 = (const float*)d_in[6];
  const float* sw3 = (const float*)d_in[7];
  float* y = (float*)d_out;
  char* ws = (char*)d_ws;

  int*   counts = (int*)(ws + 0);
  int*   ntiles = (int*)(ws + 256);
  int*   offs   = (int*)(ws + 512);
  int4*  desc   = (int4*)(ws + 768);          // 448 * 16B
  int*   tidx   = (int*)(ws + 8192);          // 49152 int
  float* tw     = (float*)(ws + 204800);      // 49152 f32
  int*   ptok   = (int*)(ws + 401408);        // 49152 int
  float* pw     = (float*)(ws + 598016);      // 49152 f32
  int*   slotof = (int*)(ws + 794624);        // 49152 int
  u16*   xb     = (u16*)(ws + 991232);        // 8192*2048 bf16
  u16*   H      = (u16*)(ws + 34545664);      // 49280*1408 bf16 (128-row pad)
  u16*   Hs     = (u16*)(ws + 173318144);     // 8192*2816 bf16
  u16*   sout   = (u16*)(ws + 219455488);     // 49152*2048 bf16  -> total ~420.8 MB

  zero32<<<1, 64, 0, stream>>>(counts);
  gate_route_k<<<2048, 256, 0, stream>>>(x, gw, tidx, tw, counts);
  cvt_x_k<<<8192, 256, 0, stream>>>(x, xb);
  scan_desc_k<<<1, 64, 0, stream>>>(counts, offs, desc, ntiles);
  perm_build_k<<<32, 256, 0, stream>>>(tidx, tw, offs, ptok, pw, slotof);

  up_gemm_k<false><<<dim3(416, 11), 256, 0, stream>>>(xb, w1, w3, ptok, desc, ntiles, H);
  up_gemm_k<true ><<<dim3(64, 22), 256, 0, stream>>>(xb, sw1, sw3, ptok, desc, ntiles, Hs);

  down_gemm_k<true ><<<dim3(64, 16), 256, 0, stream>>>(Hs, sw2, desc, ntiles, pw, sout, y);
  down_gemm_k<false><<<dim3(416, 16), 256, 0, stream>>>(H, w2, desc, ntiles, pw, sout, y);

  combine_k<<<8192, 256, 0, stream>>>(y, sout, slotof);
}

// Round 2
// 2487.430 us; speedup vs baseline: 1.3165x; 1.3165x over previous
//
#include <hip/hip_runtime.h>
#include <hip/hip_bf16.h>
#include <stdint.h>

typedef unsigned short u16;

#define T_TOK 8192
#define DIM 2048
#define INTER 1408
#define NEXP 32
#define TOPK 6
#define SHINTER 2816
#define SLOTS (T_TOK * TOPK)   // 49152

typedef __attribute__((ext_vector_type(8))) short bf16x8;
typedef __attribute__((ext_vector_type(4))) float f32x4;

__device__ inline u16 f2bf(float f) {
  union { float f; unsigned u; } c; c.f = f;
  unsigned r = (c.u + 0x7FFFu + ((c.u >> 16) & 1u)) >> 16;
  return (u16)r;
}
__device__ inline float bf2f(u16 h) {
  union { unsigned u; float f; } c; c.u = ((unsigned)h) << 16;
  return c.f;
}

__device__ __forceinline__ void gl16(const void* g, void* l) {
  __builtin_amdgcn_global_load_lds(
      (const __attribute__((address_space(1))) void*)g,
      (__attribute__((address_space(3))) void*)l, 16, 0, 0);
}

// ---------------- gate + routing ----------------
__global__ __launch_bounds__(256)
void gate_route_k(const float* __restrict__ x, const float* __restrict__ gw,
                  int* __restrict__ tidx, float* __restrict__ tw, int* __restrict__ counts)
{
  int lane = threadIdx.x & 63, w = threadIdx.x >> 6;
  int t = blockIdx.x * 4 + w;
  __shared__ float sc[4][32];
  __shared__ float gm[4][8];
  const float* xr = x + (size_t)t * DIM + lane * 4;
  float4 xv[8];
#pragma unroll
  for (int i = 0; i < 8; i++) xv[i] = *(const float4*)(xr + i * 256);
  for (int e = 0; e < NEXP; e++) {
    const float* g = gw + (size_t)e * DIM + lane * 4;
    float acc = 0.f;
#pragma unroll
    for (int i = 0; i < 8; i++) {
      float4 gv = *(const float4*)(g + i * 256);
      acc += xv[i].x * gv.x + xv[i].y * gv.y + xv[i].z * gv.z + xv[i].w * gv.w;
    }
#pragma unroll
    for (int off = 32; off > 0; off >>= 1) acc += __shfl_down(acc, off);
    if (lane == 0) sc[w][e] = 1.f / (1.f + __expf(-acc));
  }
  if (lane == 0) {
#pragma unroll
    for (int g = 0; g < 8; g++)
      gm[w][g] = fmaxf(fmaxf(sc[w][g*4+0], sc[w][g*4+1]), fmaxf(sc[w][g*4+2], sc[w][g*4+3]));
    unsigned gsel = 0u;
    for (int it = 0; it < 4; it++) {
      float best = -1.f; int bi = 0;
      for (int g = 0; g < 8; g++)
        if (!((gsel >> g) & 1u) && gm[w][g] > best) { best = gm[w][g]; bi = g; }
      gsel |= 1u << bi;
    }
    unsigned chosen = 0u; float wsum = 0.f;
    int ids[TOPK]; float wv[TOPK];
#pragma unroll
    for (int it = 0; it < TOPK; it++) {
      float best = -1.f; int bi = 0;
      for (int e = 0; e < NEXP; e++)
        if (((gsel >> (e >> 2)) & 1u) && !((chosen >> e) & 1u) && sc[w][e] > best) { best = sc[w][e]; bi = e; }
      chosen |= 1u << bi; ids[it] = bi; wv[it] = best; wsum += best;
    }
    float s = 2.5f / wsum;
#pragma unroll
    for (int k = 0; k < TOPK; k++) {
      tidx[t * TOPK + k] = ids[k];
      tw[t * TOPK + k] = wv[k] * s;
      atomicAdd(&counts[ids[k]], 1);
    }
  }
}

__global__ void zero32(int* p) { if (threadIdx.x < NEXP) p[threadIdx.x] = 0; }

// ---------------- scan + tile descriptors ----------------
__global__ void scan_desc_k(const int* __restrict__ counts, int* __restrict__ offs,
                            int4* __restrict__ desc, int* __restrict__ ntiles)
{
  if (threadIdx.x != 0 || blockIdx.x != 0) return;
  int off = 0, n = 0;
  for (int e = 0; e < NEXP; e++) {
    offs[e] = off;
    int c = counts[e];
    int nt = (c + 127) >> 7;
    for (int i = 0; i < nt; i++) {
      int rem = c - i * 128;
      desc[n] = make_int4(e, off + i * 128, rem < 128 ? rem : 128, 0);
      n++;
    }
    off += c;
  }
  offs[NEXP] = off;
  ntiles[0] = n;
}

// ---------------- deterministic permutation build ----------------
__global__ __launch_bounds__(256)
void perm_build_k(const int* __restrict__ tidx, const float* __restrict__ tw,
                  const int* __restrict__ offs, int* __restrict__ ptok,
                  float* __restrict__ pw, int* __restrict__ slotof)
{
  int e = blockIdx.x;
  int tid = threadIdx.x, lane = tid & 63, w = tid >> 6;
  __shared__ int wsum[4];
  __shared__ int cursor;
  if (tid == 0) cursor = offs[e];
  __syncthreads();
  for (int start = 0; start < SLOTS; start += 256) {
    int i = start + tid;
    int match = (tidx[i] == e) ? 1 : 0;
    unsigned long long b = __ballot(match);
    if (lane == 0) wsum[w] = __popcll(b);
    __syncthreads();
    int base = cursor;
    int waveoff = 0;
    for (int ww = 0; ww < w; ww++) waveoff += wsum[ww];
    int total = wsum[0] + wsum[1] + wsum[2] + wsum[3];
    if (match) {
      int before = __popcll(b & ((1ull << lane) - 1ull));
      int slot = base + waveoff + before;
      ptok[slot] = i / TOPK;
      pw[slot] = tw[i];
      slotof[i] = slot;
    }
    __syncthreads();
    if (tid == 0) cursor = base + total;
  }
}

// ---------------- f32 -> bf16 conversion (x and weights) ----------------
__global__ __launch_bounds__(256)
void cvt_w_k(const float* __restrict__ src, u16* __restrict__ dst, int n8)
{
  int stride = gridDim.x * 256;
  for (size_t i = (size_t)blockIdx.x * 256 + threadIdx.x; i < (size_t)n8; i += stride) {
    size_t j = i * 8;
    float4 a = *(const float4*)(src + j);
    float4 b = *(const float4*)(src + j + 4);
    union { u16 h[8]; uint4 u; } p;
    p.h[0] = f2bf(a.x); p.h[1] = f2bf(a.y); p.h[2] = f2bf(a.z); p.h[3] = f2bf(a.w);
    p.h[4] = f2bf(b.x); p.h[5] = f2bf(b.y); p.h[6] = f2bf(b.z); p.h[7] = f2bf(b.w);
    *(uint4*)(dst + j) = p.u;
  }
}

// ============================================================================
// NEW PATH: bf16 weights + global_load_lds staging + XOR-swizzled LDS
// LDS tile [128][64] bf16 linear; source pre-swizzled: chunk' = chunk^(row&7);
// frag read applies the same involution.
// ============================================================================

// fused up-GEMM: H = silu(X W1^T) * (X W3^T)
template<bool SHARED>
__global__ __launch_bounds__(256, 2)
void up2_k(const u16* __restrict__ xb,
           const u16* __restrict__ B1g, const u16* __restrict__ B3g,
           const int* __restrict__ ptok,
           const int4* __restrict__ desc, const int* __restrict__ ntiles,
           u16* __restrict__ Hout)
{
  constexpr int HLD = SHARED ? SHINTER : INTER;
  int row_tile = blockIdx.x, col_tile = blockIdx.y;
  int slot_base, rows;
  const u16 *B1, *B3;
  if constexpr (SHARED) { slot_base = row_tile * 128; rows = 128; B1 = B1g; B3 = B3g; }
  else {
    if (row_tile >= ntiles[0]) return;
    int4 d = desc[row_tile];
    slot_base = d.y; rows = d.z;
    size_t off = (size_t)d.x * (size_t)INTER * DIM;
    B1 = B1g + off; B3 = B3g + off;
  }
  int n0 = col_tile * 128;
  int tid = threadIdx.x, lane = tid & 63;
  int w = tid >> 6, wr = w >> 1, wc = w & 1;

  __shared__ u16 As[128][64];
  __shared__ u16 Bs1[128][64];
  __shared__ u16 Bs3[128][64];

  // staging: wave w -> rows [32w,32w+32), 4 instrs x 8 rows; lane l -> row l>>3.
  // swizzled source chunk = (l&7) ^ (l>>3)  (row&7 == l>>3 on the write side)
  int selem = (((lane & 7) ^ (lane >> 3)) * 8);
  const u16 *a_src[4], *b1_src[4], *b3_src[4];
#pragma unroll
  for (int s = 0; s < 4; s++) {
    int r = w * 32 + s * 8 + (lane >> 3);
    int tok;
    if constexpr (SHARED) tok = slot_base + r;
    else { int rr = r < rows ? r : rows - 1; tok = ptok[slot_base + rr]; }
    a_src[s]  = xb + (size_t)tok * DIM + selem;
    b1_src[s] = B1 + (size_t)(n0 + r) * DIM + selem;
    b3_src[s] = B3 + (size_t)(n0 + r) * DIM + selem;
  }

  f32x4 acc1[4][4], acc3[4][4];
#pragma unroll
  for (int m = 0; m < 4; m++)
#pragma unroll
    for (int n = 0; n < 4; n++) { acc1[m][n] = {0.f,0.f,0.f,0.f}; acc3[m][n] = {0.f,0.f,0.f,0.f}; }

  for (int kk = 0; kk < DIM / 64; kk++) {
    __syncthreads();
#pragma unroll
    for (int s = 0; s < 4; s++) {
      gl16(a_src[s]  + kk * 64, &As [w * 32 + s * 8][0]);
      gl16(b1_src[s] + kk * 64, &Bs1[w * 32 + s * 8][0]);
      gl16(b3_src[s] + kk * 64, &Bs3[w * 32 + s * 8][0]);
    }
    __syncthreads();   // compiler drains vmcnt before s_barrier
#pragma unroll
    for (int h = 0; h < 2; h++) {
      bf16x8 af[4], b1f[4], b3f[4];
      int chk = (h * 4 + (lane >> 4)) ^ (lane & 7);   // swizzled 16B-chunk index
#pragma unroll
      for (int m = 0; m < 4; m++)
        af[m] = *(const bf16x8*)&As[wr * 64 + m * 16 + (lane & 15)][chk * 8];
#pragma unroll
      for (int n = 0; n < 4; n++) {
        b1f[n] = *(const bf16x8*)&Bs1[wc * 64 + n * 16 + (lane & 15)][chk * 8];
        b3f[n] = *(const bf16x8*)&Bs3[wc * 64 + n * 16 + (lane & 15)][chk * 8];
      }
#pragma unroll
      for (int m = 0; m < 4; m++)
#pragma unroll
        for (int n = 0; n < 4; n++) {
          acc1[m][n] = __builtin_amdgcn_mfma_f32_16x16x32_bf16(af[m], b1f[n], acc1[m][n], 0, 0, 0);
          acc3[m][n] = __builtin_amdgcn_mfma_f32_16x16x32_bf16(af[m], b3f[n], acc3[m][n], 0, 0, 0);
        }
    }
  }
#pragma unroll
  for (int m = 0; m < 4; m++) {
#pragma unroll
    for (int r = 0; r < 4; r++) {
      int row_local = wr * 64 + m * 16 + (lane >> 4) * 4 + r;
      if (row_local < rows) {
        size_t rowp = (size_t)(slot_base + row_local) * HLD + n0 + wc * 64 + (lane & 15);
#pragma unroll
        for (int n = 0; n < 4; n++) {
          float c1 = acc1[m][n][r], c3 = acc3[m][n][r];
          float hval = (c1 / (1.f + __expf(-c1))) * c3;
          Hout[rowp + n * 16] = f2bf(hval);
        }
      }
    }
  }
}

// down-GEMM: O = H W2^T (+route-weight scale for routed path)
template<bool SHARED>
__global__ __launch_bounds__(256, 2)
void down2_k(const u16* __restrict__ Hin, const u16* __restrict__ Bg,
             const int4* __restrict__ desc, const int* __restrict__ ntiles,
             const float* __restrict__ pw,
             u16* __restrict__ slotout, float* __restrict__ yout)
{
  constexpr int KD = SHARED ? SHINTER : INTER;
  constexpr int KSTEPS = KD / 64;
  int row_tile = blockIdx.x, col_tile = blockIdx.y;
  int slot_base, rows; const u16* B;
  if constexpr (SHARED) { slot_base = row_tile * 128; rows = 128; B = Bg; }
  else {
    if (row_tile >= ntiles[0]) return;
    int4 d = desc[row_tile]; slot_base = d.y; rows = d.z;
    B = Bg + (size_t)d.x * DIM * INTER;
  }
  int n0 = col_tile * 128;
  int tid = threadIdx.x, lane = tid & 63;
  int w = tid >> 6, wr = w >> 1, wc = w & 1;
  __shared__ u16 As[128][64];
  __shared__ u16 Bs[128][64];

  int selem = (((lane & 7) ^ (lane >> 3)) * 8);
  const u16 *a_src[4], *b_src[4];
#pragma unroll
  for (int s = 0; s < 4; s++) {
    int r = w * 32 + s * 8 + (lane >> 3);
    a_src[s] = Hin + (size_t)(slot_base + r) * KD + selem;
    b_src[s] = B + (size_t)(n0 + r) * KD + selem;
  }

  f32x4 acc[4][4];
#pragma unroll
  for (int m = 0; m < 4; m++)
#pragma unroll
    for (int n = 0; n < 4; n++) acc[m][n] = {0.f,0.f,0.f,0.f};

  for (int kk = 0; kk < KSTEPS; kk++) {
    __syncthreads();
#pragma unroll
    for (int s = 0; s < 4; s++) {
      gl16(a_src[s] + kk * 64, &As[w * 32 + s * 8][0]);
      gl16(b_src[s] + kk * 64, &Bs[w * 32 + s * 8][0]);
    }
    __syncthreads();
#pragma unroll
    for (int h = 0; h < 2; h++) {
      bf16x8 af[4], bfv[4];
      int chk = (h * 4 + (lane >> 4)) ^ (lane & 7);
#pragma unroll
      for (int m = 0; m < 4; m++)
        af[m] = *(const bf16x8*)&As[wr * 64 + m * 16 + (lane & 15)][chk * 8];
#pragma unroll
      for (int n = 0; n < 4; n++)
        bfv[n] = *(const bf16x8*)&Bs[wc * 64 + n * 16 + (lane & 15)][chk * 8];
#pragma unroll
      for (int m = 0; m < 4; m++)
#pragma unroll
        for (int n = 0; n < 4; n++)
          acc[m][n] = __builtin_amdgcn_mfma_f32_16x16x32_bf16(af[m], bfv[n], acc[m][n], 0, 0, 0);
    }
  }
#pragma unroll
  for (int m = 0; m < 4; m++) {
#pragma unroll
    for (int r = 0; r < 4; r++) {
      int row_local = wr * 64 + m * 16 + (lane >> 4) * 4 + r;
      if (row_local < rows) {
        int slot = slot_base + row_local;
        size_t rp = (size_t)slot * DIM + n0 + wc * 64 + (lane & 15);
        if constexpr (SHARED) {
#pragma unroll
          for (int n = 0; n < 4; n++) yout[rp + n * 16] = acc[m][n][r];
        } else {
          float sw = pw[slot];
#pragma unroll
          for (int n = 0; n < 4; n++) slotout[rp + n * 16] = f2bf(acc[m][n][r] * sw);
        }
      }
    }
  }
}

// ============================================================================
// FALLBACK PATH (round-1, f32 weights reg-staged) — used if ws too small
// ============================================================================
template<bool SHARED>
__global__ __launch_bounds__(256, 2)
void up_gemm_k(const u16* __restrict__ xb,
               const float* __restrict__ W1g, const float* __restrict__ W3g,
               const int* __restrict__ ptok,
               const int4* __restrict__ desc, const int* __restrict__ ntiles,
               u16* __restrict__ Hout)
{
  constexpr int HLD = SHARED ? SHINTER : INTER;
  int row_tile = blockIdx.x, col_tile = blockIdx.y;
  int slot_base, rows;
  const float *B1, *B3;
  if constexpr (SHARED) {
    slot_base = row_tile * 128; rows = 128; B1 = W1g; B3 = W3g;
  } else {
    if (row_tile >= ntiles[0]) return;
    int4 d = desc[row_tile];
    slot_base = d.y; rows = d.z;
    size_t off = (size_t)d.x * (size_t)INTER * DIM;
    B1 = W1g + off; B3 = W3g + off;
  }
  int n0 = col_tile * 128;
  int tid = threadIdx.x, lane = tid & 63;
  int wv = tid >> 6, wr = wv >> 1, wc = wv & 1;

  __shared__ u16 As[128][72];
  __shared__ u16 Bs1[128][72];
  __shared__ u16 Bs3[128][72];

  int ar = tid >> 3, ac = (tid & 7) * 8;
  const u16* asrc[4];
#pragma unroll
  for (int s = 0; s < 4; s++) {
    int r = s * 32 + ar;
    int tok;
    if constexpr (SHARED) tok = slot_base + r;
    else { int rr = r < rows ? r : rows - 1; tok = ptok[slot_base + rr]; }
    asrc[s] = xb + (size_t)tok * DIM + ac;
  }
  int br = tid >> 4, bc = (tid & 15) * 4;
  const float* b1p = B1 + (size_t)(n0 + br) * DIM + bc;
  const float* b3p = B3 + (size_t)(n0 + br) * DIM + bc;

  f32x4 acc1[4][4], acc3[4][4];
#pragma unroll
  for (int m = 0; m < 4; m++)
#pragma unroll
    for (int n = 0; n < 4; n++) { acc1[m][n] = {0.f,0.f,0.f,0.f}; acc3[m][n] = {0.f,0.f,0.f,0.f}; }

  for (int kk = 0; kk < DIM / 64; kk++) {
    __syncthreads();
#pragma unroll
    for (int s = 0; s < 4; s++) {
      uint4 v = *(const uint4*)(asrc[s] + kk * 64);
      *(uint4*)&As[s * 32 + ar][ac] = v;
    }
#pragma unroll
    for (int s = 0; s < 8; s++) {
      float4 v = *(const float4*)(b1p + (size_t)(s * 16) * DIM + kk * 64);
      union { u16 h[4]; uint2 q; } o;
      o.h[0] = f2bf(v.x); o.h[1] = f2bf(v.y); o.h[2] = f2bf(v.z); o.h[3] = f2bf(v.w);
      *(uint2*)&Bs1[s * 16 + br][bc] = o.q;
    }
#pragma unroll
    for (int s = 0; s < 8; s++) {
      float4 v = *(const float4*)(b3p + (size_t)(s * 16) * DIM + kk * 64);
      union { u16 h[4]; uint2 q; } o;
      o.h[0] = f2bf(v.x); o.h[1] = f2bf(v.y); o.h[2] = f2bf(v.z); o.h[3] = f2bf(v.w);
      *(uint2*)&Bs3[s * 16 + br][bc] = o.q;
    }
    __syncthreads();
#pragma unroll
    for (int h = 0; h < 2; h++) {
      bf16x8 af[4], b1f[4], b3f[4];
#pragma unroll
      for (int m = 0; m < 4; m++)
        af[m] = *(const bf16x8*)&As[wr * 64 + m * 16 + (lane & 15)][h * 32 + (lane >> 4) * 8];
#pragma unroll
      for (int n = 0; n < 4; n++) {
        b1f[n] = *(const bf16x8*)&Bs1[wc * 64 + n * 16 + (lane & 15)][h * 32 + (lane >> 4) * 8];
        b3f[n] = *(const bf16x8*)&Bs3[wc * 64 + n * 16 + (lane & 15)][h * 32 + (lane >> 4) * 8];
      }
#pragma unroll
      for (int m = 0; m < 4; m++)
#pragma unroll
        for (int n = 0; n < 4; n++) {
          acc1[m][n] = __builtin_amdgcn_mfma_f32_16x16x32_bf16(af[m], b1f[n], acc1[m][n], 0, 0, 0);
          acc3[m][n] = __builtin_amdgcn_mfma_f32_16x16x32_bf16(af[m], b3f[n], acc3[m][n], 0, 0, 0);
        }
    }
  }
#pragma unroll
  for (int m = 0; m < 4; m++) {
#pragma unroll
    for (int r = 0; r < 4; r++) {
      int row_local = wr * 64 + m * 16 + (lane >> 4) * 4 + r;
      if (row_local < rows) {
        size_t rowp = (size_t)(slot_base + row_local) * HLD + n0 + wc * 64 + (lane & 15);
#pragma unroll
        for (int n = 0; n < 4; n++) {
          float c1 = acc1[m][n][r], c3 = acc3[m][n][r];
          float hval = (c1 / (1.f + __expf(-c1))) * c3;
          Hout[rowp + n * 16] = f2bf(hval);
        }
      }
    }
  }
}

template<bool SHARED>
__global__ __launch_bounds__(256, 2)
void down_gemm_k(const u16* __restrict__ Hin, const float* __restrict__ Bg,
                 const int4* __restrict__ desc, const int* __restrict__ ntiles,
                 const float* __restrict__ pw,
                 u16* __restrict__ slotout, float* __restrict__ yout)
{
  constexpr int KD = SHARED ? SHINTER : INTER;
  constexpr int KSTEPS = KD / 64;
  int row_tile = blockIdx.x, col_tile = blockIdx.y;
  int slot_base, rows; const float* B;
  if constexpr (SHARED) { slot_base = row_tile * 128; rows = 128; B = Bg; }
  else {
    if (row_tile >= ntiles[0]) return;
    int4 d = desc[row_tile]; slot_base = d.y; rows = d.z;
    B = Bg + (size_t)d.x * DIM * INTER;
  }
  int n0 = col_tile * 128;
  int tid = threadIdx.x, lane = tid & 63;
  int wv = tid >> 6, wr = wv >> 1, wc = wv & 1;
  __shared__ u16 As[128][72];
  __shared__ u16 Bs[128][72];
  int ar = tid >> 3, ac = (tid & 7) * 8;
  const u16* asrc[4];
#pragma unroll
  for (int s = 0; s < 4; s++)
    asrc[s] = Hin + (size_t)(slot_base + s * 32 + ar) * KD + ac;
  int br = tid >> 4, bc = (tid & 15) * 4;
  const float* bp = B + (size_t)(n0 + br) * KD + bc;

  f32x4 acc[4][4];
#pragma unroll
  for (int m = 0; m < 4; m++)
#pragma unroll
    for (int n = 0; n < 4; n++) acc[m][n] = {0.f,0.f,0.f,0.f};

  for (int kk = 0; kk < KSTEPS; kk++) {
    __syncthreads();
#pragma unroll
    for (int s = 0; s < 4; s++) {
      uint4 v = *(const uint4*)(asrc[s] + kk * 64);
      *(uint4*)&As[s * 32 + ar][ac] = v;
    }
#pragma unroll
    for (int s = 0; s < 8; s++) {
      float4 v = *(const float4*)(bp + (size_t)(s * 16) * KD + kk * 64);
      union { u16 h[4]; uint2 q; } o;
      o.h[0] = f2bf(v.x); o.h[1] = f2bf(v.y); o.h[2] = f2bf(v.z); o.h[3] = f2bf(v.w);
      *(uint2*)&Bs[s * 16 + br][bc] = o.q;
    }
    __syncthreads();
#pragma unroll
    for (int h = 0; h < 2; h++) {
      bf16x8 af[4], bfv[4];
#pragma unroll
      for (int m = 0; m < 4; m++)
        af[m] = *(const bf16x8*)&As[wr * 64 + m * 16 + (lane & 15)][h * 32 + (lane >> 4) * 8];
#pragma unroll
      for (int n = 0; n < 4; n++)
        bfv[n] = *(const bf16x8*)&Bs[wc * 64 + n * 16 + (lane & 15)][h * 32 + (lane >> 4) * 8];
#pragma unroll
      for (int m = 0; m < 4; m++)
#pragma unroll
        for (int n = 0; n < 4; n++)
          acc[m][n] = __builtin_amdgcn_mfma_f32_16x16x32_bf16(af[m], bfv[n], acc[m][n], 0, 0, 0);
    }
  }
#pragma unroll
  for (int m = 0; m < 4; m++) {
#pragma unroll
    for (int r = 0; r < 4; r++) {
      int row_local = wr * 64 + m * 16 + (lane >> 4) * 4 + r;
      if (row_local < rows) {
        int slot = slot_base + row_local;
        size_t rp = (size_t)slot * DIM + n0 + wc * 64 + (lane & 15);
        if constexpr (SHARED) {
#pragma unroll
          for (int n = 0; n < 4; n++) yout[rp + n * 16] = acc[m][n][r];
        } else {
          float sw = pw[slot];
#pragma unroll
          for (int n = 0; n < 4; n++) slotout[rp + n * 16] = f2bf(acc[m][n][r] * sw);
        }
      }
    }
  }
}

// ---------------- final combine: y[t] = shared + sum_k slotout ----------------
__global__ __launch_bounds__(256)
void combine_k(float* __restrict__ y, const u16* __restrict__ slotout, const int* __restrict__ slotof)
{
  int t = blockIdx.x;
  int c = threadIdx.x * 8;
  size_t rp = (size_t)t * DIM + c;
  float4 a = *(const float4*)(y + rp);
  float4 b = *(const float4*)(y + rp + 4);
  float o[8] = {a.x, a.y, a.z, a.w, b.x, b.y, b.z, b.w};
#pragma unroll
  for (int k = 0; k < TOPK; k++) {
    int s = slotof[t * TOPK + k];
    uint4 v = *(const uint4*)(slotout + (size_t)s * DIM + c);
    o[0] += bf2f((u16)(v.x & 0xFFFFu)); o[1] += bf2f((u16)(v.x >> 16));
    o[2] += bf2f((u16)(v.y & 0xFFFFu)); o[3] += bf2f((u16)(v.y >> 16));
    o[4] += bf2f((u16)(v.z & 0xFFFFu)); o[5] += bf2f((u16)(v.z >> 16));
    o[6] += bf2f((u16)(v.w & 0xFFFFu)); o[7] += bf2f((u16)(v.w >> 16));
  }
  *(float4*)(y + rp)     = make_float4(o[0], o[1], o[2], o[3]);
  *(float4*)(y + rp + 4) = make_float4(o[4], o[5], o[6], o[7]);
}

// ---------------- host ----------------
extern "C" void kernel_launch(void* const* d_in, const int* in_sizes, int n_in,
                              void* d_out, int out_size, void* d_ws, size_t ws_size,
                              hipStream_t stream)
{
  const float* x   = (const float*)d_in[0];
  const float* gw  = (const float*)d_in[1];
  const float* w1  = (const float*)d_in[2];
  const float* w2  = (const float*)d_in[3];
  const float* w3  = (const float*)d_in[4];
  const float* sw1 = (const float*)d_in[5];
  const float* sw2 = (const float*)d_in[6];
  const float* sw3 = (const float*)d_in[7];
  float* y = (float*)d_out;
  char* ws = (char*)d_ws;

  int*   counts = (int*)(ws + 0);
  int*   ntiles = (int*)(ws + 256);
  int*   offs   = (int*)(ws + 512);
  int4*  desc   = (int4*)(ws + 768);
  int*   tidx   = (int*)(ws + 8192);
  float* tw     = (float*)(ws + 204800);
  int*   ptok   = (int*)(ws + 401408);
  float* pw     = (float*)(ws + 598016);
  int*   slotof = (int*)(ws + 794624);
  u16*   xb     = (u16*)(ws + 991232);                 // 8192*2048 bf16
  u16*   H      = (u16*)(ws + 34545664ull);            // 49280*1408 bf16
  u16*   Hs     = (u16*)(ws + 173318144ull);           // 8192*2816 bf16
  u16*   sout   = (u16*)(ws + 219455488ull);           // 49152*2048 bf16
  // bf16 weight region (new path only)
  u16*   w1b    = (u16*)(ws + 420782080ull);           // 32*1408*2048
  u16*   w3b    = (u16*)(ws + 605331456ull);
  u16*   w2b    = (u16*)(ws + 789880832ull);
  u16*   sw1b   = (u16*)(ws + 974430208ull);           // 2816*2048
  u16*   sw3b   = (u16*)(ws + 985964544ull);
  u16*   sw2b   = (u16*)(ws + 997498880ull);
  const unsigned long long NEED_FULL = 1009033216ull;

  zero32<<<1, 64, 0, stream>>>(counts);
  gate_route_k<<<2048, 256, 0, stream>>>(x, gw, tidx, tw, counts);
  cvt_w_k<<<2048, 256, 0, stream>>>(x, xb, T_TOK * DIM / 8);
  scan_desc_k<<<1, 64, 0, stream>>>(counts, offs, desc, ntiles);
  perm_build_k<<<32, 256, 0, stream>>>(tidx, tw, offs, ptok, pw, slotof);

  if (ws_size >= NEED_FULL) {
    const int NW = NEXP * INTER * DIM / 8;       // 11,534,336
    const int NS = SHINTER * DIM / 8;            // 720,896
    cvt_w_k<<<4096, 256, 0, stream>>>(w1,  w1b,  NW);
    cvt_w_k<<<4096, 256, 0, stream>>>(w3,  w3b,  NW);
    cvt_w_k<<<4096, 256, 0, stream>>>(w2,  w2b,  NW);
    cvt_w_k<<<1024, 256, 0, stream>>>(sw1, sw1b, NS);
    cvt_w_k<<<1024, 256, 0, stream>>>(sw3, sw3b, NS);
    cvt_w_k<<<1024, 256, 0, stream>>>(sw2, sw2b, NS);

    up2_k<false><<<dim3(416, 11), 256, 0, stream>>>(xb, w1b, w3b, ptok, desc, ntiles, H);
    up2_k<true ><<<dim3(64, 22), 256, 0, stream>>>(xb, sw1b, sw3b, ptok, desc, ntiles, Hs);
    down2_k<true ><<<dim3(64, 16), 256, 0, stream>>>(Hs, sw2b, desc, ntiles, pw, sout, y);
    down2_k<false><<<dim3(416, 16), 256, 0, stream>>>(H, w2b, desc, ntiles, pw, sout, y);
  } else {
    up_gemm_k<false><<<dim3(416, 11), 256, 0, stream>>>(xb, w1, w3, ptok, desc, ntiles, H);
    up_gemm_k<true ><<<dim3(64, 22), 256, 0, stream>>>(xb, sw1, sw3, ptok, desc, ntiles, Hs);
    down_gemm_k<true ><<<dim3(64, 16), 256, 0, stream>>>(Hs, sw2, desc, ntiles, pw, sout, y);
    down_gemm_k<false><<<dim3(416, 16), 256, 0, stream>>>(H, w2, desc, ntiles, pw, sout, y);
  }

  combine_k<<<8192, 256, 0, stream>>>(y, sout, slotof);
}

// Round 3
// 2320.255 us; speedup vs baseline: 1.4114x; 1.0721x over previous
//
#include <hip/hip_runtime.h>
#include <hip/hip_bf16.h>
#include <stdint.h>

typedef unsigned short u16;

#define T_TOK 8192
#define DIM 2048
#define INTER 1408
#define NEXP 32
#define TOPK 6
#define SHINTER 2816
#define SLOTS (T_TOK * TOPK)   // 49152

typedef __attribute__((ext_vector_type(8))) short bf16x8;
typedef __attribute__((ext_vector_type(4))) float f32x4;

__device__ inline u16 f2bf(float f) {
  union { float f; unsigned u; } c; c.f = f;
  unsigned r = (c.u + 0x7FFFu + ((c.u >> 16) & 1u)) >> 16;
  return (u16)r;
}
__device__ inline float bf2f(u16 h) {
  union { unsigned u; float f; } c; c.u = ((unsigned)h) << 16;
  return c.f;
}

__device__ __forceinline__ void gl16(const void* g, void* l) {
  __builtin_amdgcn_global_load_lds(
      (const __attribute__((address_space(1))) void*)g,
      (__attribute__((address_space(3))) void*)l, 16, 0, 0);
}

// ---------------- gate + routing ----------------
__global__ __launch_bounds__(256)
void gate_route_k(const float* __restrict__ x, const float* __restrict__ gw,
                  int* __restrict__ tidx, float* __restrict__ tw, int* __restrict__ counts)
{
  int lane = threadIdx.x & 63, w = threadIdx.x >> 6;
  int t = blockIdx.x * 4 + w;
  __shared__ float sc[4][32];
  __shared__ float gm[4][8];
  const float* xr = x + (size_t)t * DIM + lane * 4;
  float4 xv[8];
#pragma unroll
  for (int i = 0; i < 8; i++) xv[i] = *(const float4*)(xr + i * 256);
  for (int e = 0; e < NEXP; e++) {
    const float* g = gw + (size_t)e * DIM + lane * 4;
    float acc = 0.f;
#pragma unroll
    for (int i = 0; i < 8; i++) {
      float4 gv = *(const float4*)(g + i * 256);
      acc += xv[i].x * gv.x + xv[i].y * gv.y + xv[i].z * gv.z + xv[i].w * gv.w;
    }
#pragma unroll
    for (int off = 32; off > 0; off >>= 1) acc += __shfl_down(acc, off);
    if (lane == 0) sc[w][e] = 1.f / (1.f + __expf(-acc));
  }
  if (lane == 0) {
#pragma unroll
    for (int g = 0; g < 8; g++)
      gm[w][g] = fmaxf(fmaxf(sc[w][g*4+0], sc[w][g*4+1]), fmaxf(sc[w][g*4+2], sc[w][g*4+3]));
    unsigned gsel = 0u;
    for (int it = 0; it < 4; it++) {
      float best = -1.f; int bi = 0;
      for (int g = 0; g < 8; g++)
        if (!((gsel >> g) & 1u) && gm[w][g] > best) { best = gm[w][g]; bi = g; }
      gsel |= 1u << bi;
    }
    unsigned chosen = 0u; float wsum = 0.f;
    int ids[TOPK]; float wv[TOPK];
#pragma unroll
    for (int it = 0; it < TOPK; it++) {
      float best = -1.f; int bi = 0;
      for (int e = 0; e < NEXP; e++)
        if (((gsel >> (e >> 2)) & 1u) && !((chosen >> e) & 1u) && sc[w][e] > best) { best = sc[w][e]; bi = e; }
      chosen |= 1u << bi; ids[it] = bi; wv[it] = best; wsum += best;
    }
    float s = 2.5f / wsum;
#pragma unroll
    for (int k = 0; k < TOPK; k++) {
      tidx[t * TOPK + k] = ids[k];
      tw[t * TOPK + k] = wv[k] * s;
      atomicAdd(&counts[ids[k]], 1);
    }
  }
}

__global__ void zero32(int* p) { if (threadIdx.x < NEXP) p[threadIdx.x] = 0; }

// ---------------- scan + tile descriptors (128 for fallback, 256 for main) ----
__global__ void scan_desc_k(const int* __restrict__ counts, int* __restrict__ offs,
                            int4* __restrict__ desc128, int4* __restrict__ desc256,
                            int* __restrict__ ntiles)
{
  if (threadIdx.x != 0 || blockIdx.x != 0) return;
  int off = 0, n1 = 0, n2 = 0;
  for (int e = 0; e < NEXP; e++) {
    offs[e] = off;
    int c = counts[e];
    int nt1 = (c + 127) >> 7;
    for (int i = 0; i < nt1; i++) {
      int rem = c - i * 128;
      desc128[n1++] = make_int4(e, off + i * 128, rem < 128 ? rem : 128, 0);
    }
    int nt2 = (c + 255) >> 8;
    for (int i = 0; i < nt2; i++) {
      int rem = c - i * 256;
      desc256[n2++] = make_int4(e, off + i * 256, rem < 256 ? rem : 256, 0);
    }
    off += c;
  }
  offs[NEXP] = off;
  ntiles[0] = n1;
  ntiles[1] = n2;
}

// ---------------- deterministic permutation build ----------------
__global__ __launch_bounds__(256)
void perm_build_k(const int* __restrict__ tidx, const float* __restrict__ tw,
                  const int* __restrict__ offs, int* __restrict__ ptok,
                  float* __restrict__ pw, int* __restrict__ slotof)
{
  int e = blockIdx.x;
  int tid = threadIdx.x, lane = tid & 63, w = tid >> 6;
  __shared__ int wsum[4];
  __shared__ int cursor;
  if (tid == 0) cursor = offs[e];
  __syncthreads();
  for (int start = 0; start < SLOTS; start += 256) {
    int i = start + tid;
    int match = (tidx[i] == e) ? 1 : 0;
    unsigned long long b = __ballot(match);
    if (lane == 0) wsum[w] = __popcll(b);
    __syncthreads();
    int base = cursor;
    int waveoff = 0;
    for (int ww = 0; ww < w; ww++) waveoff += wsum[ww];
    int total = wsum[0] + wsum[1] + wsum[2] + wsum[3];
    if (match) {
      int before = __popcll(b & ((1ull << lane) - 1ull));
      int slot = base + waveoff + before;
      ptok[slot] = i / TOPK;
      pw[slot] = tw[i];
      slotof[i] = slot;
    }
    __syncthreads();
    if (tid == 0) cursor = base + total;
  }
}

// ---------------- f32 -> bf16 conversion ----------------
__global__ __launch_bounds__(256)
void cvt_w_k(const float* __restrict__ src, u16* __restrict__ dst, int n8)
{
  int stride = gridDim.x * 256;
  for (size_t i = (size_t)blockIdx.x * 256 + threadIdx.x; i < (size_t)n8; i += stride) {
    size_t j = i * 8;
    float4 a = *(const float4*)(src + j);
    float4 b = *(const float4*)(src + j + 4);
    union { u16 h[8]; uint4 u; } p;
    p.h[0] = f2bf(a.x); p.h[1] = f2bf(a.y); p.h[2] = f2bf(a.z); p.h[3] = f2bf(a.w);
    p.h[4] = f2bf(b.x); p.h[5] = f2bf(b.y); p.h[6] = f2bf(b.z); p.h[7] = f2bf(b.w);
    *(uint4*)(dst + j) = p.u;
  }
}

// ============================================================================
// MAIN PATH: 256x256 tile, BK=32, 4-deep LDS pipeline, counted vmcnt,
// XCD-swizzled row tiles. 512 threads = 8 waves (2M x 4N), per-wave 128x64.
// LDS swizzle: LDS[r][chunk d] = global[r][d ^ ((r>>1)&3)]  (16B chunks, 64B rows)
// ============================================================================

// fused up-GEMM: H = silu(X W1^T) * (X W3^T); B-tile rows interleave W1/W3 at
// 16-row granularity so each wave holds (C1,C3) pairs in-register.
template<bool SHARED>
__global__ __launch_bounds__(512, 2)
void up8_k(const u16* __restrict__ xb,
           const u16* __restrict__ B1g, const u16* __restrict__ B3g,
           const int* __restrict__ ptok,
           const int4* __restrict__ desc, const int* __restrict__ ntiles,
           u16* __restrict__ Hout)
{
  constexpr int HLD = SHARED ? SHINTER : INTER;
  constexpr int NT = DIM / 32;                        // 64 K-tiles
  int rt0 = blockIdx.x;
  int row_tile = (rt0 & 7) * (int)(gridDim.x >> 3) + (rt0 >> 3);   // XCD swizzle
  int slot_base, rows;
  const u16 *B1, *B3;
  if constexpr (SHARED) { slot_base = row_tile * 256; rows = 256; B1 = B1g; B3 = B3g; }
  else {
    if (row_tile >= ntiles[1]) return;
    int4 d = desc[row_tile];
    slot_base = d.y; rows = d.z;
    size_t off = (size_t)d.x * (size_t)INTER * DIM;
    B1 = B1g + off; B3 = B3g + off;
  }
  int n0 = blockIdx.y * 128;                          // 128 inter cols per block
  int tid = threadIdx.x, lane = tid & 63, w = tid >> 6;
  int wr = w >> 2, wcn = w & 3;

  __shared__ u16 As[4][256][32];                      // 64 KB
  __shared__ u16 Bs[4][256][32];                      // 64 KB

  // staging sources: per wave 2 A-instrs + 2 B-instrs per K-tile (16 rows each)
  const u16 *pA[2], *pB[2];
#pragma unroll
  for (int s = 0; s < 2; s++) {
    int rl = w * 32 + s * 16 + (lane >> 2);           // LDS tile row for this lane
    int sc = (((lane & 3) ^ ((rl >> 1) & 3)) * 8);    // pre-swizzled source chunk
    int tok;
    if constexpr (SHARED) tok = slot_base + rl;
    else tok = ptok[slot_base + (rl < rows ? rl : rows - 1)];
    pA[s] = xb + (size_t)tok * DIM + sc;
    const u16* mb = (s == 0) ? B1 : B3;               // B row 16-block (2w+s): mat = s
    pB[s] = mb + (size_t)(n0 + w * 16 + (lane >> 2)) * DIM + sc;
  }

  f32x4 acc[8][4];
#pragma unroll
  for (int m = 0; m < 8; m++)
#pragma unroll
    for (int n = 0; n < 4; n++) acc[m][n] = {0.f, 0.f, 0.f, 0.f};

  auto STAGE = [&](int t) {
    int b = t & 3, ko = t * 32;
    gl16(pA[0] + ko, &As[b][w * 32][0]);
    gl16(pA[1] + ko, &As[b][w * 32 + 16][0]);
    gl16(pB[0] + ko, &Bs[b][w * 32][0]);
    gl16(pB[1] + ko, &Bs[b][w * 32 + 16][0]);
  };
  STAGE(0); STAGE(1); STAGE(2);

  int ccol = (((lane >> 4) ^ ((lane >> 1) & 3)) * 8); // swizzled read chunk (row-indep)
  for (int t = 0; t < NT; ++t) {
    if (t < NT - 2)       asm volatile("s_waitcnt vmcnt(8)" ::: "memory");
    else if (t == NT - 2) asm volatile("s_waitcnt vmcnt(4)" ::: "memory");
    else                  asm volatile("s_waitcnt vmcnt(0)" ::: "memory");
    __builtin_amdgcn_s_barrier();
    int b = t & 3;
    bf16x8 af[8], bv[4];
#pragma unroll
    for (int m = 0; m < 8; m++)
      af[m] = *(const bf16x8*)&As[b][wr * 128 + m * 16 + (lane & 15)][ccol];
#pragma unroll
    for (int n = 0; n < 4; n++)
      bv[n] = *(const bf16x8*)&Bs[b][wcn * 64 + n * 16 + (lane & 15)][ccol];
    if (t + 3 < NT) STAGE(t + 3);
    __builtin_amdgcn_s_setprio(1);
#pragma unroll
    for (int m = 0; m < 8; m++)
#pragma unroll
      for (int n = 0; n < 4; n++)
        acc[m][n] = __builtin_amdgcn_mfma_f32_16x16x32_bf16(af[m], bv[n], acc[m][n], 0, 0, 0);
    __builtin_amdgcn_s_setprio(0);
  }

  // epilogue: pair (C1,C3) in-register, silu-mul, write bf16 H
#pragma unroll
  for (int m = 0; m < 8; m++) {
#pragma unroll
    for (int j = 0; j < 2; j++) {
      f32x4 c1 = acc[m][2 * j], c3 = acc[m][2 * j + 1];
      int col = n0 + (wcn * 2 + j) * 16 + (lane & 15);
#pragma unroll
      for (int r = 0; r < 4; r++) {
        int row_local = wr * 128 + m * 16 + (lane >> 4) * 4 + r;
        if (row_local < rows) {
          float v1 = c1[r], v3 = c3[r];
          Hout[(size_t)(slot_base + row_local) * HLD + col] =
              f2bf((v1 / (1.f + __expf(-v1))) * v3);
        }
      }
    }
  }
}

// down-GEMM: O = H W2^T (+route-weight scale for routed path)
template<bool SHARED>
__global__ __launch_bounds__(512, 2)
void down8_k(const u16* __restrict__ Hin, const u16* __restrict__ Bg,
             const int4* __restrict__ desc, const int* __restrict__ ntiles,
             const float* __restrict__ pw,
             u16* __restrict__ slotout, float* __restrict__ yout)
{
  constexpr int KD = SHARED ? SHINTER : INTER;
  constexpr int NT = KD / 32;                         // 88 / 44
  int rt0 = blockIdx.x;
  int row_tile = (rt0 & 7) * (int)(gridDim.x >> 3) + (rt0 >> 3);
  int slot_base, rows; const u16* B;
  if constexpr (SHARED) { slot_base = row_tile * 256; rows = 256; B = Bg; }
  else {
    if (row_tile >= ntiles[1]) return;
    int4 d = desc[row_tile]; slot_base = d.y; rows = d.z;
    B = Bg + (size_t)d.x * DIM * INTER;
  }
  int n0 = blockIdx.y * 256;
  int tid = threadIdx.x, lane = tid & 63, w = tid >> 6;
  int wr = w >> 2, wcn = w & 3;

  __shared__ u16 As[4][256][32];
  __shared__ u16 Bs[4][256][32];

  const u16 *pA[2], *pB[2];
#pragma unroll
  for (int s = 0; s < 2; s++) {
    int rl = w * 32 + s * 16 + (lane >> 2);
    int sc = (((lane & 3) ^ ((rl >> 1) & 3)) * 8);
    pA[s] = Hin + (size_t)(slot_base + rl) * KD + sc;
    pB[s] = B + (size_t)(n0 + rl) * KD + sc;
  }

  f32x4 acc[8][4];
#pragma unroll
  for (int m = 0; m < 8; m++)
#pragma unroll
    for (int n = 0; n < 4; n++) acc[m][n] = {0.f, 0.f, 0.f, 0.f};

  auto STAGE = [&](int t) {
    int b = t & 3, ko = t * 32;
    gl16(pA[0] + ko, &As[b][w * 32][0]);
    gl16(pA[1] + ko, &As[b][w * 32 + 16][0]);
    gl16(pB[0] + ko, &Bs[b][w * 32][0]);
    gl16(pB[1] + ko, &Bs[b][w * 32 + 16][0]);
  };
  STAGE(0); STAGE(1); STAGE(2);

  int ccol = (((lane >> 4) ^ ((lane >> 1) & 3)) * 8);
  for (int t = 0; t < NT; ++t) {
    if (t < NT - 2)       asm volatile("s_waitcnt vmcnt(8)" ::: "memory");
    else if (t == NT - 2) asm volatile("s_waitcnt vmcnt(4)" ::: "memory");
    else                  asm volatile("s_waitcnt vmcnt(0)" ::: "memory");
    __builtin_amdgcn_s_barrier();
    int b = t & 3;
    bf16x8 af[8], bv[4];
#pragma unroll
    for (int m = 0; m < 8; m++)
      af[m] = *(const bf16x8*)&As[b][wr * 128 + m * 16 + (lane & 15)][ccol];
#pragma unroll
    for (int n = 0; n < 4; n++)
      bv[n] = *(const bf16x8*)&Bs[b][wcn * 64 + n * 16 + (lane & 15)][ccol];
    if (t + 3 < NT) STAGE(t + 3);
    __builtin_amdgcn_s_setprio(1);
#pragma unroll
    for (int m = 0; m < 8; m++)
#pragma unroll
      for (int n = 0; n < 4; n++)
        acc[m][n] = __builtin_amdgcn_mfma_f32_16x16x32_bf16(af[m], bv[n], acc[m][n], 0, 0, 0);
    __builtin_amdgcn_s_setprio(0);
  }

#pragma unroll
  for (int m = 0; m < 8; m++) {
#pragma unroll
    for (int n = 0; n < 4; n++) {
      int col = n0 + (wcn * 4 + n) * 16 + (lane & 15);
#pragma unroll
      for (int r = 0; r < 4; r++) {
        int row_local = wr * 128 + m * 16 + (lane >> 4) * 4 + r;
        if (row_local < rows) {
          int slot = slot_base + row_local;
          if constexpr (SHARED) {
            yout[(size_t)slot * DIM + col] = acc[m][n][r];
          } else {
            slotout[(size_t)slot * DIM + col] = f2bf(acc[m][n][r] * pw[slot]);
          }
        }
      }
    }
  }
}

// ============================================================================
// FALLBACK PATH (f32 weights, 128^2 reg-staged) — used only if ws too small
// ============================================================================
template<bool SHARED>
__global__ __launch_bounds__(256, 2)
void up_gemm_k(const u16* __restrict__ xb,
               const float* __restrict__ W1g, const float* __restrict__ W3g,
               const int* __restrict__ ptok,
               const int4* __restrict__ desc, const int* __restrict__ ntiles,
               u16* __restrict__ Hout)
{
  constexpr int HLD = SHARED ? SHINTER : INTER;
  int row_tile = blockIdx.x, col_tile = blockIdx.y;
  int slot_base, rows;
  const float *B1, *B3;
  if constexpr (SHARED) {
    slot_base = row_tile * 128; rows = 128; B1 = W1g; B3 = W3g;
  } else {
    if (row_tile >= ntiles[0]) return;
    int4 d = desc[row_tile];
    slot_base = d.y; rows = d.z;
    size_t off = (size_t)d.x * (size_t)INTER * DIM;
    B1 = W1g + off; B3 = W3g + off;
  }
  int n0 = col_tile * 128;
  int tid = threadIdx.x, lane = tid & 63;
  int wv = tid >> 6, wr = wv >> 1, wc = wv & 1;

  __shared__ u16 As[128][72];
  __shared__ u16 Bs1[128][72];
  __shared__ u16 Bs3[128][72];

  int ar = tid >> 3, ac = (tid & 7) * 8;
  const u16* asrc[4];
#pragma unroll
  for (int s = 0; s < 4; s++) {
    int r = s * 32 + ar;
    int tok;
    if constexpr (SHARED) tok = slot_base + r;
    else { int rr = r < rows ? r : rows - 1; tok = ptok[slot_base + rr]; }
    asrc[s] = xb + (size_t)tok * DIM + ac;
  }
  int br = tid >> 4, bc = (tid & 15) * 4;
  const float* b1p = B1 + (size_t)(n0 + br) * DIM + bc;
  const float* b3p = B3 + (size_t)(n0 + br) * DIM + bc;

  f32x4 acc1[4][4], acc3[4][4];
#pragma unroll
  for (int m = 0; m < 4; m++)
#pragma unroll
    for (int n = 0; n < 4; n++) { acc1[m][n] = {0.f,0.f,0.f,0.f}; acc3[m][n] = {0.f,0.f,0.f,0.f}; }

  for (int kk = 0; kk < DIM / 64; kk++) {
    __syncthreads();
#pragma unroll
    for (int s = 0; s < 4; s++) {
      uint4 v = *(const uint4*)(asrc[s] + kk * 64);
      *(uint4*)&As[s * 32 + ar][ac] = v;
    }
#pragma unroll
    for (int s = 0; s < 8; s++) {
      float4 v = *(const float4*)(b1p + (size_t)(s * 16) * DIM + kk * 64);
      union { u16 h[4]; uint2 q; } o;
      o.h[0] = f2bf(v.x); o.h[1] = f2bf(v.y); o.h[2] = f2bf(v.z); o.h[3] = f2bf(v.w);
      *(uint2*)&Bs1[s * 16 + br][bc] = o.q;
    }
#pragma unroll
    for (int s = 0; s < 8; s++) {
      float4 v = *(const float4*)(b3p + (size_t)(s * 16) * DIM + kk * 64);
      union { u16 h[4]; uint2 q; } o;
      o.h[0] = f2bf(v.x); o.h[1] = f2bf(v.y); o.h[2] = f2bf(v.z); o.h[3] = f2bf(v.w);
      *(uint2*)&Bs3[s * 16 + br][bc] = o.q;
    }
    __syncthreads();
#pragma unroll
    for (int h = 0; h < 2; h++) {
      bf16x8 af[4], b1f[4], b3f[4];
#pragma unroll
      for (int m = 0; m < 4; m++)
        af[m] = *(const bf16x8*)&As[wr * 64 + m * 16 + (lane & 15)][h * 32 + (lane >> 4) * 8];
#pragma unroll
      for (int n = 0; n < 4; n++) {
        b1f[n] = *(const bf16x8*)&Bs1[wc * 64 + n * 16 + (lane & 15)][h * 32 + (lane >> 4) * 8];
        b3f[n] = *(const bf16x8*)&Bs3[wc * 64 + n * 16 + (lane & 15)][h * 32 + (lane >> 4) * 8];
      }
#pragma unroll
      for (int m = 0; m < 4; m++)
#pragma unroll
        for (int n = 0; n < 4; n++) {
          acc1[m][n] = __builtin_amdgcn_mfma_f32_16x16x32_bf16(af[m], b1f[n], acc1[m][n], 0, 0, 0);
          acc3[m][n] = __builtin_amdgcn_mfma_f32_16x16x32_bf16(af[m], b3f[n], acc3[m][n], 0, 0, 0);
        }
    }
  }
#pragma unroll
  for (int m = 0; m < 4; m++) {
#pragma unroll
    for (int r = 0; r < 4; r++) {
      int row_local = wr * 64 + m * 16 + (lane >> 4) * 4 + r;
      if (row_local < rows) {
        size_t rowp = (size_t)(slot_base + row_local) * HLD + n0 + wc * 64 + (lane & 15);
#pragma unroll
        for (int n = 0; n < 4; n++) {
          float c1 = acc1[m][n][r], c3 = acc3[m][n][r];
          float hval = (c1 / (1.f + __expf(-c1))) * c3;
          Hout[rowp + n * 16] = f2bf(hval);
        }
      }
    }
  }
}

template<bool SHARED>
__global__ __launch_bounds__(256, 2)
void down_gemm_k(const u16* __restrict__ Hin, const float* __restrict__ Bg,
                 const int4* __restrict__ desc, const int* __restrict__ ntiles,
                 const float* __restrict__ pw,
                 u16* __restrict__ slotout, float* __restrict__ yout)
{
  constexpr int KD = SHARED ? SHINTER : INTER;
  constexpr int KSTEPS = KD / 64;
  int row_tile = blockIdx.x, col_tile = blockIdx.y;
  int slot_base, rows; const float* B;
  if constexpr (SHARED) { slot_base = row_tile * 128; rows = 128; B = Bg; }
  else {
    if (row_tile >= ntiles[0]) return;
    int4 d = desc[row_tile]; slot_base = d.y; rows = d.z;
    B = Bg + (size_t)d.x * DIM * INTER;
  }
  int n0 = col_tile * 128;
  int tid = threadIdx.x, lane = tid & 63;
  int wv = tid >> 6, wr = wv >> 1, wc = wv & 1;
  __shared__ u16 As[128][72];
  __shared__ u16 Bs[128][72];
  int ar = tid >> 3, ac = (tid & 7) * 8;
  const u16* asrc[4];
#pragma unroll
  for (int s = 0; s < 4; s++)
    asrc[s] = Hin + (size_t)(slot_base + s * 32 + ar) * KD + ac;
  int br = tid >> 4, bc = (tid & 15) * 4;
  const float* bp = B + (size_t)(n0 + br) * KD + bc;

  f32x4 acc[4][4];
#pragma unroll
  for (int m = 0; m < 4; m++)
#pragma unroll
    for (int n = 0; n < 4; n++) acc[m][n] = {0.f,0.f,0.f,0.f};

  for (int kk = 0; kk < KSTEPS; kk++) {
    __syncthreads();
#pragma unroll
    for (int s = 0; s < 4; s++) {
      uint4 v = *(const uint4*)(asrc[s] + kk * 64);
      *(uint4*)&As[s * 32 + ar][ac] = v;
    }
#pragma unroll
    for (int s = 0; s < 8; s++) {
      float4 v = *(const float4*)(bp + (size_t)(s * 16) * KD + kk * 64);
      union { u16 h[4]; uint2 q; } o;
      o.h[0] = f2bf(v.x); o.h[1] = f2bf(v.y); o.h[2] = f2bf(v.z); o.h[3] = f2bf(v.w);
      *(uint2*)&Bs[s * 16 + br][bc] = o.q;
    }
    __syncthreads();
#pragma unroll
    for (int h = 0; h < 2; h++) {
      bf16x8 af[4], bfv[4];
#pragma unroll
      for (int m = 0; m < 4; m++)
        af[m] = *(const bf16x8*)&As[wr * 64 + m * 16 + (lane & 15)][h * 32 + (lane >> 4) * 8];
#pragma unroll
      for (int n = 0; n < 4; n++)
        bfv[n] = *(const bf16x8*)&Bs[wc * 64 + n * 16 + (lane & 15)][h * 32 + (lane >> 4) * 8];
#pragma unroll
      for (int m = 0; m < 4; m++)
#pragma unroll
        for (int n = 0; n < 4; n++)
          acc[m][n] = __builtin_amdgcn_mfma_f32_16x16x32_bf16(af[m], bfv[n], acc[m][n], 0, 0, 0);
    }
  }
#pragma unroll
  for (int m = 0; m < 4; m++) {
#pragma unroll
    for (int r = 0; r < 4; r++) {
      int row_local = wr * 64 + m * 16 + (lane >> 4) * 4 + r;
      if (row_local < rows) {
        int slot = slot_base + row_local;
        size_t rp = (size_t)slot * DIM + n0 + wc * 64 + (lane & 15);
        if constexpr (SHARED) {
#pragma unroll
          for (int n = 0; n < 4; n++) yout[rp + n * 16] = acc[m][n][r];
        } else {
          float sw = pw[slot];
#pragma unroll
          for (int n = 0; n < 4; n++) slotout[rp + n * 16] = f2bf(acc[m][n][r] * sw);
        }
      }
    }
  }
}

// ---------------- final combine: y[t] = shared + sum_k slotout ----------------
__global__ __launch_bounds__(256)
void combine_k(float* __restrict__ y, const u16* __restrict__ slotout, const int* __restrict__ slotof)
{
  int t = blockIdx.x;
  int c = threadIdx.x * 8;
  size_t rp = (size_t)t * DIM + c;
  float4 a = *(const float4*)(y + rp);
  float4 b = *(const float4*)(y + rp + 4);
  float o[8] = {a.x, a.y, a.z, a.w, b.x, b.y, b.z, b.w};
#pragma unroll
  for (int k = 0; k < TOPK; k++) {
    int s = slotof[t * TOPK + k];
    uint4 v = *(const uint4*)(slotout + (size_t)s * DIM + c);
    o[0] += bf2f((u16)(v.x & 0xFFFFu)); o[1] += bf2f((u16)(v.x >> 16));
    o[2] += bf2f((u16)(v.y & 0xFFFFu)); o[3] += bf2f((u16)(v.y >> 16));
    o[4] += bf2f((u16)(v.z & 0xFFFFu)); o[5] += bf2f((u16)(v.z >> 16));
    o[6] += bf2f((u16)(v.w & 0xFFFFu)); o[7] += bf2f((u16)(v.w >> 16));
  }
  *(float4*)(y + rp)     = make_float4(o[0], o[1], o[2], o[3]);
  *(float4*)(y + rp + 4) = make_float4(o[4], o[5], o[6], o[7]);
}

// ---------------- host ----------------
extern "C" void kernel_launch(void* const* d_in, const int* in_sizes, int n_in,
                              void* d_out, int out_size, void* d_ws, size_t ws_size,
                              hipStream_t stream)
{
  const float* x   = (const float*)d_in[0];
  const float* gw  = (const float*)d_in[1];
  const float* w1  = (const float*)d_in[2];
  const float* w2  = (const float*)d_in[3];
  const float* w3  = (const float*)d_in[4];
  const float* sw1 = (const float*)d_in[5];
  const float* sw2 = (const float*)d_in[6];
  const float* sw3 = (const float*)d_in[7];
  float* y = (float*)d_out;
  char* ws = (char*)d_ws;

  int*   counts  = (int*)(ws + 0);
  int*   ntiles  = (int*)(ws + 256);
  int*   offs    = (int*)(ws + 512);
  int4*  desc128 = (int4*)(ws + 1024);            // 448*16 -> 8192
  int4*  desc256 = (int4*)(ws + 8192);            // 224*16 -> 11776
  int*   tidx    = (int*)(ws + 16384);            // -> 212992
  float* tw      = (float*)(ws + 212992);         // -> 409600
  int*   ptok    = (int*)(ws + 409600);           // -> 606208
  float* pw      = (float*)(ws + 606208);         // -> 802816
  int*   slotof  = (int*)(ws + 802816);           // -> 999424
  u16*   xb      = (u16*)(ws + 1048576);          // 8192*2048 bf16 -> 34603008
  u16*   H       = (u16*)(ws + 34603008ull);      // 49408*1408 bf16 -> 173735936
  u16*   Hs      = (u16*)(ws + 173735936ull);     // 8192*2816 bf16 -> 219873280
  u16*   sout    = (u16*)(ws + 219873280ull);     // 49152*2048 bf16 -> 421199872
  u16*   w1b     = (u16*)(ws + 421199872ull);
  u16*   w3b     = (u16*)(ws + 605749248ull);
  u16*   w2b     = (u16*)(ws + 790298624ull);
  u16*   sw1b    = (u16*)(ws + 974848000ull);
  u16*   sw3b    = (u16*)(ws + 986382336ull);
  u16*   sw2b    = (u16*)(ws + 997916672ull);
  const unsigned long long NEED_FULL = 1009451008ull;

  zero32<<<1, 64, 0, stream>>>(counts);
  gate_route_k<<<2048, 256, 0, stream>>>(x, gw, tidx, tw, counts);
  cvt_w_k<<<2048, 256, 0, stream>>>(x, xb, T_TOK * DIM / 8);
  scan_desc_k<<<1, 64, 0, stream>>>(counts, offs, desc128, desc256, ntiles);
  perm_build_k<<<32, 256, 0, stream>>>(tidx, tw, offs, ptok, pw, slotof);

  if (ws_size >= NEED_FULL) {
    const int NW = NEXP * INTER * DIM / 8;
    const int NS = SHINTER * DIM / 8;
    cvt_w_k<<<4096, 256, 0, stream>>>(w1,  w1b,  NW);
    cvt_w_k<<<4096, 256, 0, stream>>>(w3,  w3b,  NW);
    cvt_w_k<<<4096, 256, 0, stream>>>(w2,  w2b,  NW);
    cvt_w_k<<<1024, 256, 0, stream>>>(sw1, sw1b, NS);
    cvt_w_k<<<1024, 256, 0, stream>>>(sw3, sw3b, NS);
    cvt_w_k<<<1024, 256, 0, stream>>>(sw2, sw2b, NS);

    up8_k<false><<<dim3(224, 11), 512, 0, stream>>>(xb, w1b, w3b, ptok, desc256, ntiles, H);
    up8_k<true ><<<dim3(32, 22), 512, 0, stream>>>(xb, sw1b, sw3b, ptok, desc256, ntiles, Hs);
    down8_k<true ><<<dim3(32, 8), 512, 0, stream>>>(Hs, sw2b, desc256, ntiles, pw, sout, y);
    down8_k<false><<<dim3(224, 8), 512, 0, stream>>>(H, w2b, desc256, ntiles, pw, sout, y);
  } else {
    up_gemm_k<false><<<dim3(416, 11), 256, 0, stream>>>(xb, w1, w3, ptok, desc128, ntiles, H);
    up_gemm_k<true ><<<dim3(64, 22), 256, 0, stream>>>(xb, sw1, sw3, ptok, desc128, ntiles, Hs);
    down_gemm_k<true ><<<dim3(64, 16), 256, 0, stream>>>(Hs, sw2, desc128, ntiles, pw, sout, y);
    down_gemm_k<false><<<dim3(416, 16), 256, 0, stream>>>(H, w2, desc128, ntiles, pw, sout, y);
  }

  combine_k<<<8192, 256, 0, stream>>>(y, sout, slotof);
}